// Round 14
// baseline (5637.320 us; speedup 1.0000x reference)
//
#include <hip/hip_runtime.h>
#include <stdint.h>

// LSTM autoencoder: B=64, T=256, P=128, H=512, LAT=128
// out = [x_hat (64*256*128 f32), z (64*128 f32)]
// R14 = R13 (5.16 ms) + per-wave tags: waves 2/3 each store their own tag
// right after their own vmcnt drain (per-wave counter). Post-gate barrier
// deleted. Encoder poll: 32 tags (wave0 lanes 0-31). Decoder: 64 own tags
// (wave0, all lanes) + 64 producer tags (wave1, fused only).

typedef unsigned short u16;
typedef unsigned int u32;
typedef float f32x4 __attribute__((ext_vector_type(4)));
typedef __bf16 bf16x8 __attribute__((ext_vector_type(8)));
typedef unsigned int u32x4 __attribute__((ext_vector_type(4)));

#define AT_LD(p) __hip_atomic_load((p), __ATOMIC_RELAXED, __HIP_MEMORY_SCOPE_AGENT)
#define AT_ST(p, v) __hip_atomic_store((p), (v), __ATOMIC_RELAXED, __HIP_MEMORY_SCOPE_AGENT)

__device__ __forceinline__ u16 f2bf(float f) {
  u32 u = __builtin_bit_cast(u32, f);
  u += 0x7FFFu + ((u >> 16) & 1u);
  return (u16)(u >> 16);
}
__device__ __forceinline__ float bf2f(u16 h) {
  return __builtin_bit_cast(float, (u32)h << 16);
}
__device__ __forceinline__ bf16x8 ld8(const u16* p) {
  u32x4 v = *(const u32x4*)p;
  return __builtin_bit_cast(bf16x8, v);
}
__device__ __forceinline__ float sigf(float x) { return 1.f / (1.f + __expf(-x)); }
__device__ __forceinline__ float tanhx(float x) {
  x = fminf(fmaxf(x, -15.f), 15.f);
  float e = __expf(2.f * x);
  return (e - 1.f) / (e + 1.f);
}

// ---- prep kernels ----
__global__ void k_prep_x(const float* __restrict__ x, const float* __restrict__ st,
                         u16* __restrict__ Ax, u16* __restrict__ Axs, int n) {
  int i = blockIdx.x * 256 + threadIdx.x;
  if (i >= n) return;
  Ax[i] = f2bf(x[i]);
  int col = i & 127;
  int t = (i >> 7) & 255;
  float v = (t == 0) ? st[col] : x[i - 128];
  Axs[i] = f2bf(v);
}

// merged f32->bf16 conversions (13 jobs, prefix table)
struct CvtJobs {
  const float* src[13];
  u16* dst[13];
  int off[14];
};
__global__ void k_cvt_all(CvtJobs j, int total) {
  int i = blockIdx.x * 256 + threadIdx.x;
  if (i >= total) return;
  int a = 0;
#pragma unroll
  for (int k = 1; k < 13; ++k) a += (i >= j.off[k]) ? 1 : 0;
  int local = i - j.off[a];
  j.dst[a][local] = f2bf(j.src[a][local]);
}

// ---- bulk GEMM: C[M][N] = A[M][K] @ B'[N][K]^T + bias, bf16 in, fp32 acc ----
__global__ __launch_bounds__(256) void k_gemm_bt(
    const u16* __restrict__ A, const u16* __restrict__ B, const float* __restrict__ bias,
    u16* __restrict__ Cb, float* __restrict__ Cf, int M, int N, int K, int sig) {
  __shared__ __align__(16) u16 As[128 * 64];
  __shared__ __align__(16) u16 Bs[128 * 64];
  const int m0 = blockIdx.x * 128, n0 = blockIdx.y * 128;
  const int tid = threadIdx.x, lane = tid & 63, wave = tid >> 6;
  const int wm = wave >> 1, wn = wave & 1;

  f32x4 acc[4][4];
#pragma unroll
  for (int i = 0; i < 4; ++i)
#pragma unroll
    for (int j = 0; j < 4; ++j) acc[i][j] = (f32x4){0.f, 0.f, 0.f, 0.f};

  const int nkt = K >> 6;
  for (int kt = 0; kt < nkt; ++kt) {
#pragma unroll
    for (int i = 0; i < 4; ++i) {
      int ch = tid + (i << 8);
      int row = ch >> 3, k8 = ch & 7;
      int dst = row * 128 + ((k8 * 16) ^ ((row & 7) << 4));
      u32x4 va = *(const u32x4*)(A + (size_t)(m0 + row) * K + kt * 64 + k8 * 8);
      *(u32x4*)((char*)As + dst) = va;
      u32x4 vb = *(const u32x4*)(B + (size_t)(n0 + row) * K + kt * 64 + k8 * 8);
      *(u32x4*)((char*)Bs + dst) = vb;
    }
    __syncthreads();
#pragma unroll
    for (int kk = 0; kk < 2; ++kk) {
      int kb = kk * 64 + ((lane >> 4) << 4);
      bf16x8 afr[4], bfr[4];
#pragma unroll
      for (int i = 0; i < 4; ++i) {
        int ra = wm * 64 + i * 16 + (lane & 15);
        afr[i] = ld8((const u16*)((const char*)As + ra * 128 + (kb ^ ((ra & 7) << 4))));
        int rb = wn * 64 + i * 16 + (lane & 15);
        bfr[i] = ld8((const u16*)((const char*)Bs + rb * 128 + (kb ^ ((rb & 7) << 4))));
      }
#pragma unroll
      for (int i = 0; i < 4; ++i)
#pragma unroll
        for (int j = 0; j < 4; ++j)
          acc[i][j] = __builtin_amdgcn_mfma_f32_16x16x32_bf16(afr[i], bfr[j], acc[i][j], 0, 0, 0);
    }
    __syncthreads();
  }
#pragma unroll
  for (int i = 0; i < 4; ++i) {
#pragma unroll
    for (int j = 0; j < 4; ++j) {
      int col = n0 + wn * 64 + j * 16 + (lane & 15);
      float bv = bias ? bias[col] : 0.f;
#pragma unroll
      for (int r = 0; r < 4; ++r) {
        int row = m0 + wm * 64 + i * 16 + ((lane >> 4) << 2) + r;
        float v = acc[i][j][r] + bv;
        if (sig) Cf[(size_t)row * N + col] = 1.f / (1.f + __expf(-v));
        else     Cb[(size_t)row * N + col] = f2bf(v);
      }
    }
  }
}

// ---- encoder recurrence: 16-block chains (32 h-cols each), per-wave tags ----
struct RecE {
  const u16* xW[8];
  const u16* Whh[8];
  u16* seq[8];
  float* hfin[8];
  u16* hxc[8];
  int seqstride[8]; int coloff[8]; int rev[8]; int hfinstride[8];
  int grp[8];
  u32* tags;             // [chain][64]; writer c uses slots c*2, c*2+1
};

__global__ __launch_bounds__(256, 1) void k_rec_e(RecE p) {
  const int chain = blockIdx.x & 7;
  const int c = blockIdx.x >> 3;  // 0..15
  const int tid = threadIdx.x, lane = tid & 63, wave = tid >> 6;  // wave = gate
  const int arow = lane & 15, kg = lane >> 4;

  const u16* __restrict__ xW = p.xW[chain];
  const u16* __restrict__ Whh = p.Whh[chain];
  u16* seq = p.seq[chain];
  float* hfin = p.hfin[chain];
  u32* hx = (u32*)p.hxc[chain];
  const int grp = p.grp[chain], rev = p.rev[chain];
  const int sstride = p.seqstride[chain], coloff = p.coloff[chain];
  const int hstride = p.hfinstride[chain];
  u32* myt = p.tags + chain * 64;

  __shared__ __align__(16) u16 Wlds[64][128][8];  // [k>>3][n][k&7], n=gate*32+col
  __shared__ __align__(16) u16 hbufA[8192];
  __shared__ float gbuf[4][16][32];
  __shared__ float cbuf[512];

  for (int e = tid; e < 8192; e += 256) {
    int n = e >> 6, k8 = e & 63;
    int grow = ((n >> 5) << 9) + (c << 5) + (n & 31);
    *(u32x4*)(&Wlds[k8][n][0]) = *(const u32x4*)(Whh + (size_t)grow * 512 + k8 * 8);
  }
  for (int e = tid; e < 512; e += 256) cbuf[e] = 0.f;
  for (int e = tid; e < 4096; e += 256) AT_ST(hx + e, 0u);
  asm volatile("s_waitcnt vmcnt(0)" ::: "memory");
  __syncthreads();
  if (tid == 0) { AT_ST(myt + c * 2, 1u); AT_ST(myt + c * 2 + 1, 1u); }

  for (int t = 0; t < 256; ++t) {
    const int t_eff = rev ? 255 - t : t;
    const int slot = t & 3;
    const int slotn = (t + 1) & 3;

    float xwv[4][2];
#pragma unroll
    for (int r4 = 0; r4 < 4; ++r4) {
      int row = (kg << 2) + r4;
      const u16* xwp = xW + (((size_t)((grp * 16 + row) * 256 + t_eff)) << 11) +
                       (wave << 9) + (c << 5);
      xwv[r4][0] = bf2f(xwp[arow]);
      xwv[r4][1] = bf2f(xwp[arow + 16]);
    }
    // poll: wave 0, lanes 0-31 cover 16 writers x 2 tags (own included)
    if (wave == 0) {
      u32 thr = (u32)(t + 1);
      while (true) {
        int ok = 1;
        if (lane < 32) ok = (AT_LD(myt + lane) >= thr);
        if (__all(ok)) break;
        __builtin_amdgcn_s_sleep(1);
      }
    }
    __syncthreads();  // #1
    __builtin_amdgcn_sched_barrier(0);

#pragma unroll
    for (int i = 0; i < 4; ++i) {
      int cid = tid + (i << 8);
      int row = cid >> 6, ch8 = cid & 63;
      const u32* src = hx + slot * 4096 + row * 256 + ch8 * 4;
      u32x4 v;
      v.x = AT_LD(src + 0); v.y = AT_LD(src + 1);
      v.z = AT_LD(src + 2); v.w = AT_LD(src + 3);
      *(u32x4*)((char*)hbufA + row * 1024 + ((ch8 << 4) ^ ((row & 7) << 4))) = v;
    }
    __syncthreads();  // #2

    bf16x8 af[16];
#pragma unroll
    for (int kt = 0; kt < 16; ++kt)
      af[kt] = ld8((const u16*)((const char*)hbufA + arow * 1024 +
                                ((kt * 64 + (kg << 4)) ^ ((arow & 7) << 4))));
    f32x4 acc0 = {0.f, 0.f, 0.f, 0.f};
    f32x4 acc1 = {0.f, 0.f, 0.f, 0.f};
#pragma unroll
    for (int kt = 0; kt < 16; ++kt) {
      const u16* bp = &Wlds[(kt << 2) + kg][(wave << 5) + arow][0];
      bf16x8 b0 = ld8(bp);
      bf16x8 b1 = ld8(bp + 128);
      acc0 = __builtin_amdgcn_mfma_f32_16x16x32_bf16(af[kt], b0, acc0, 0, 0, 0);
      acc1 = __builtin_amdgcn_mfma_f32_16x16x32_bf16(af[kt], b1, acc1, 0, 0, 0);
    }
#pragma unroll
    for (int r4 = 0; r4 < 4; ++r4) {
      gbuf[wave][(kg << 2) + r4][arow] = acc0[r4] + xwv[r4][0];
      gbuf[wave][(kg << 2) + r4][arow + 16] = acc1[r4] + xwv[r4][1];
    }
    __syncthreads();  // #3: gbuf complete

    // gate math + publish + PER-WAVE tag (no barrier before tag)
    if (tid >= 128) {
      int t2 = tid - 128;
      int row2 = t2 >> 3; int q = t2 & 7; int j0 = q << 2;
      float hhv[4];
#pragma unroll
      for (int jj = 0; jj < 4; ++jj) {
        int col = j0 + jj;
        float iv = gbuf[0][row2][col];
        float fv = gbuf[1][row2][col];
        float gv = gbuf[2][row2][col];
        float ov = gbuf[3][row2][col];
        int ci = (row2 << 5) + col;
        float cc = sigf(fv) * cbuf[ci] + sigf(iv) * tanhx(gv);
        cbuf[ci] = cc;
        hhv[jj] = sigf(ov) * tanhx(cc);
      }
      u32 pk0 = (u32)f2bf(hhv[0]) | ((u32)f2bf(hhv[1]) << 16);
      u32 pk1 = (u32)f2bf(hhv[2]) | ((u32)f2bf(hhv[3]) << 16);
      u32* dst = hx + slotn * 4096 + row2 * 256 + (c << 4) + (q << 1);
      AT_ST(dst, pk0);
      AT_ST(dst + 1, pk1);
      asm volatile("s_waitcnt vmcnt(0)" ::: "memory");  // per-wave drain
      if (lane == 0) AT_ST(myt + c * 2 + (wave - 2), (u32)(t + 2));
      // bulk outputs after the tag
      if (seq) {
        u32* sp = (u32*)(seq + ((size_t)((grp * 16 + row2) * 256 + t_eff)) * sstride +
                         coloff + (c << 5) + j0);
        sp[0] = pk0; sp[1] = pk1;
      }
      if (hfin && t == 255) {
        float* hp = hfin + (size_t)(grp * 16 + row2) * hstride + (c << 5) + j0;
        hp[0] = hhv[0]; hp[1] = hhv[1]; hp[2] = hhv[2]; hp[3] = hhv[3];
      }
    }
    // no barrier here: loop-top #1/#2 guard gbuf/hbufA reuse
  }
}

// ---- decoder recurrence (32-block chains, fused d0||d1, per-wave tags) ----
struct Rec2 {
  const u16* xW[8];
  const u16* Whh[8];
  const u16* Wih[8];
  const float* bias[8];
  const float* h0[8];
  u16* seq[8];
  float* hfin[8];
  u16* hxc[8];
  int prod[8];
  int seqstride[8]; int coloff[8]; int rev[8]; int hfinstride[8];
  int grp[8]; int fused[8]; int fullp[8];
  u32* tags;             // [chain][64]; writer c uses slots c*2, c*2+1
};

__global__ __launch_bounds__(256, 1) void k_rec2(Rec2 p) {
  const int chain = blockIdx.x & 7;
  const int c = blockIdx.x >> 3;  // 0..31
  const int tid = threadIdx.x, lane = tid & 63, wave = tid >> 6;  // wave = gate
  const int arow = lane & 15, kg = lane >> 4;

  const u16* __restrict__ xW = p.xW[chain];
  const u16* __restrict__ Whh = p.Whh[chain];
  const u16* __restrict__ Wih = p.Wih[chain];
  const float* __restrict__ bias = p.bias[chain];
  const float* __restrict__ h0 = p.h0[chain];
  u16* seq = p.seq[chain];
  float* hfin = p.hfin[chain];
  u32* hx = (u32*)p.hxc[chain];
  const u32* hxp = (const u32*)p.hxc[p.prod[chain]];
  const int grp = p.grp[chain], rev = p.rev[chain];
  const int fused = p.fused[chain], fullp = p.fullp[chain];
  const int sstride = p.seqstride[chain], coloff = p.coloff[chain];
  const int hstride = p.hfinstride[chain];
  u32* myt = p.tags + chain * 64;
  const u32* pt = p.tags + p.prod[chain] * 64;

  __shared__ __align__(16) u16 Wlds[64][64][8];
  __shared__ __align__(16) u16 Xlds[64][64][8];
  __shared__ __align__(16) u16 hbufA[8192];
  __shared__ float gbuf[4][16][16];
  __shared__ float cbuf[256];
  __shared__ float bbuf[64];

  for (int e = tid; e < 4096; e += 256) {
    int n = e >> 6, k8 = e & 63;
    int grow = ((n >> 4) << 9) + (c << 4) + (n & 15);
    *(u32x4*)(&Wlds[k8][n][0]) = *(const u32x4*)(Whh + (size_t)grow * 512 + k8 * 8);
    if (fused)
      *(u32x4*)(&Xlds[k8][n][0]) = *(const u32x4*)(Wih + (size_t)grow * 512 + k8 * 8);
  }
  if (tid < 64) bbuf[tid] = fused ? bias[((tid >> 4) << 9) + (c << 4) + (tid & 15)] : 0.f;
  cbuf[tid] = 0.f;
  if (tid < 128) {
    int row = tid >> 3, q = tid & 7;
    float a = 0.f, b2 = 0.f;
    if (h0) {
      a = h0[(size_t)(grp * 16 + row) * 512 + (c << 4) + 2 * q];
      b2 = h0[(size_t)(grp * 16 + row) * 512 + (c << 4) + 2 * q + 1];
    }
    u32 pk = (u32)f2bf(a) | ((u32)f2bf(b2) << 16);
    AT_ST(hx + (size_t)c * 128 + (row << 3) + q, pk);
  }
  asm volatile("s_waitcnt vmcnt(0)" ::: "memory");
  __syncthreads();
  if (tid == 0) { AT_ST(myt + c * 2, 1u); AT_ST(myt + c * 2 + 1, 1u); }

  for (int t = 0; t < 256; ++t) {
    const int t_eff = rev ? 255 - t : t;
    const int slot = fullp ? t : (t & 3);
    const int slotn = fullp ? (t + 1) : ((t + 1) & 3);

    float xwv[4] = {0.f, 0.f, 0.f, 0.f};
    if (!fused) {
#pragma unroll
      for (int r4 = 0; r4 < 4; ++r4) {
        int row = (kg << 2) + r4;
        xwv[r4] = bf2f(xW[(((size_t)((grp * 16 + row) * 256 + t_eff)) << 11) +
                          (wave << 9) + (c << 4) + arow]);
      }
    }
    // poll: wave 0 covers 64 own tags (32 writers x 2, own included);
    // wave 1 covers 64 producer tags (fused only).
    if (wave == 0) {
      u32 thr_own = (u32)(t + 1);
      while (true) {
        int ok = (AT_LD(myt + lane) >= thr_own);
        if (__all(ok)) break;
        __builtin_amdgcn_s_sleep(1);
      }
    } else if (wave == 1 && fused) {
      u32 thr_prod = (u32)(t + 2);
      while (true) {
        int ok = (AT_LD(pt + lane) >= thr_prod);
        if (__all(ok)) break;
        __builtin_amdgcn_s_sleep(1);
      }
    }
    __syncthreads();  // #1
    __builtin_amdgcn_sched_barrier(0);

#pragma unroll
    for (int i = 0; i < 4; ++i) {
      int cid = tid + (i << 8);
      int row = cid >> 6, ch8 = cid & 63;
      const u32* src = hx + ((size_t)slot * 32 + (ch8 >> 1)) * 128 +
                       (row << 3) + ((ch8 & 1) << 2);
      u32x4 v;
      v.x = AT_LD(src + 0); v.y = AT_LD(src + 1);
      v.z = AT_LD(src + 2); v.w = AT_LD(src + 3);
      *(u32x4*)((char*)hbufA + row * 1024 + ((ch8 << 4) ^ ((row & 7) << 4))) = v;
    }
    bf16x8 xf[16];
    if (fused) {
#pragma unroll
      for (int kt = 0; kt < 16; ++kt) {
        const u32* hp = hxp + ((size_t)(t + 1) * 32 + 2 * kt + (kg >> 1)) * 128 +
                        (arow << 3) + ((kg & 1) << 2);
        u32x4 v;
        v.x = AT_LD(hp + 0); v.y = AT_LD(hp + 1);
        v.z = AT_LD(hp + 2); v.w = AT_LD(hp + 3);
        xf[kt] = __builtin_bit_cast(bf16x8, v);
      }
    }
    __syncthreads();  // #2

    bf16x8 af[16];
#pragma unroll
    for (int kt = 0; kt < 16; ++kt)
      af[kt] = ld8((const u16*)((const char*)hbufA + arow * 1024 +
                                ((kt * 64 + (kg << 4)) ^ ((arow & 7) << 4))));
    f32x4 ae = {0.f, 0.f, 0.f, 0.f}, ao = {0.f, 0.f, 0.f, 0.f};
#pragma unroll
    for (int kt = 0; kt < 16; ++kt) {
      bf16x8 bw = ld8(&Wlds[(kt << 2) + kg][(wave << 4) + arow][0]);
      if (kt & 1) ao = __builtin_amdgcn_mfma_f32_16x16x32_bf16(af[kt], bw, ao, 0, 0, 0);
      else        ae = __builtin_amdgcn_mfma_f32_16x16x32_bf16(af[kt], bw, ae, 0, 0, 0);
      if (fused) {
        bf16x8 bx = ld8(&Xlds[(kt << 2) + kg][(wave << 4) + arow][0]);
        if (kt & 1) ae = __builtin_amdgcn_mfma_f32_16x16x32_bf16(xf[kt], bx, ae, 0, 0, 0);
        else        ao = __builtin_amdgcn_mfma_f32_16x16x32_bf16(xf[kt], bx, ao, 0, 0, 0);
      }
    }
#pragma unroll
    for (int r4 = 0; r4 < 4; ++r4)
      gbuf[wave][(kg << 2) + r4][arow] = ae[r4] + ao[r4] + xwv[r4];
    __syncthreads();  // #3: gbuf complete

    // gate math + publish + PER-WAVE tag (no barrier before tag)
    if (tid >= 128) {
      int t2 = tid - 128;
      int row2 = t2 >> 3; int q = t2 & 7; int j0 = q << 1;
      float i0 = gbuf[0][row2][j0], i1 = gbuf[0][row2][j0 + 1];
      float f0 = gbuf[1][row2][j0], f1 = gbuf[1][row2][j0 + 1];
      float g0 = gbuf[2][row2][j0], g1 = gbuf[2][row2][j0 + 1];
      float o0v = gbuf[3][row2][j0], o1v = gbuf[3][row2][j0 + 1];
      if (fused) {
        i0 += bbuf[j0]; i1 += bbuf[j0 + 1];
        f0 += bbuf[16 + j0]; f1 += bbuf[16 + j0 + 1];
        g0 += bbuf[32 + j0]; g1 += bbuf[32 + j0 + 1];
        o0v += bbuf[48 + j0]; o1v += bbuf[48 + j0 + 1];
      }
      int ci = (row2 << 4) + j0;
      float cc0 = sigf(f0) * cbuf[ci] + sigf(i0) * tanhx(g0);
      float cc1 = sigf(f1) * cbuf[ci + 1] + sigf(i1) * tanhx(g1);
      cbuf[ci] = cc0; cbuf[ci + 1] = cc1;
      float hh0 = sigf(o0v) * tanhx(cc0);
      float hh1 = sigf(o1v) * tanhx(cc1);
      u32 pk = (u32)f2bf(hh0) | ((u32)f2bf(hh1) << 16);
      AT_ST(hx + ((size_t)slotn * 32 + c) * 128 + (row2 << 3) + q, pk);
      asm volatile("s_waitcnt vmcnt(0)" ::: "memory");  // per-wave drain
      if (lane == 0) AT_ST(myt + c * 2 + (wave - 2), (u32)(t + 2));
      if (seq)
        *(u32*)(seq + ((size_t)((grp * 16 + row2) * 256 + t_eff)) * sstride +
                coloff + (c << 4) + j0) = pk;
      if (hfin && t == 255) {
        hfin[(size_t)(grp * 16 + row2) * hstride + (c << 4) + j0] = hh0;
        hfin[(size_t)(grp * 16 + row2) * hstride + (c << 4) + j0 + 1] = hh1;
      }
    }
    // no barrier here: loop-top #1/#2 guard gbuf/hbufA reuse
  }
}

// ---- tiny heads ----
__global__ void k_enc_head(const float* __restrict__ hcat, const float* __restrict__ W,
                           const float* __restrict__ b, float* __restrict__ zws,
                           float* __restrict__ zout) {
  int bi = blockIdx.x, j = threadIdx.x;
  const float* h = hcat + bi * 1024;
  const float* w = W + j * 1024;
  float s = b[j];
  for (int k = 0; k < 1024; ++k) s += h[k] * w[k];
  zws[bi * 128 + j] = s;
  zout[bi * 128 + j] = s;
}

__global__ void k_dec_head(const float* __restrict__ z, const float* __restrict__ W,
                           const float* __restrict__ b, float* __restrict__ h0d) {
  int bi = blockIdx.x, j = threadIdx.x;
  const float* zz = z + bi * 128;
  const float* w = W + j * 128;
  float s = b[j];
  for (int k = 0; k < 128; ++k) s += zz[k] * w[k];
  h0d[bi * 512 + j] = s;
}

extern "C" void kernel_launch(void* const* d_in, const int* in_sizes, int n_in,
                              void* d_out, int out_size, void* d_ws, size_t ws_size,
                              hipStream_t stream) {
  (void)in_sizes; (void)n_in; (void)out_size;
  const float* x        = (const float*)d_in[0];
  const float* e0f_Wih  = (const float*)d_in[1];
  const float* e0f_Whh  = (const float*)d_in[2];
  const float* e0f_b    = (const float*)d_in[3];
  const float* e0b_Wih  = (const float*)d_in[4];
  const float* e0b_Whh  = (const float*)d_in[5];
  const float* e0b_b    = (const float*)d_in[6];
  const float* e1f_Wih  = (const float*)d_in[7];
  const float* e1f_Whh  = (const float*)d_in[8];
  const float* e1f_b    = (const float*)d_in[9];
  const float* e1b_Wih  = (const float*)d_in[10];
  const float* e1b_Whh  = (const float*)d_in[11];
  const float* e1b_b    = (const float*)d_in[12];
  const float* enc_fc_W = (const float*)d_in[13];
  const float* enc_fc_b = (const float*)d_in[14];
  const float* dec_fc_W = (const float*)d_in[15];
  const float* dec_fc_b = (const float*)d_in[16];
  const float* start_tk = (const float*)d_in[17];
  const float* d0_Wih   = (const float*)d_in[18];
  const float* d0_Whh   = (const float*)d_in[19];
  const float* d0_b     = (const float*)d_in[20];
  const float* d1_Wih   = (const float*)d_in[21];
  const float* d1_Whh   = (const float*)d_in[22];
  const float* d1_b     = (const float*)d_in[23];
  const float* out_W    = (const float*)d_in[24];
  const float* out_b    = (const float*)d_in[25];

  uintptr_t base = (uintptr_t)d_ws;
  size_t off = 0;
  auto carve = [&](size_t bytes) -> void* {
    off = (off + 255) & ~(size_t)255;
    void* p = (void*)(base + off);
    off += bytes;
    return p;
  };
  u16* Ax     = (u16*)carve((size_t)2097152 * 2);
  u16* Axs    = (u16*)carve((size_t)2097152 * 2);
  u16* Wb_e0f = (u16*)carve((size_t)262144 * 2);
  u16* Wb_e0b = (u16*)carve((size_t)262144 * 2);
  u16* Wb_d0  = (u16*)carve((size_t)262144 * 2);
  u16* Wb_e1f = (u16*)carve((size_t)2097152 * 2);
  u16* Wb_e1b = (u16*)carve((size_t)2097152 * 2);
  u16* Wb_d1  = (u16*)carve((size_t)1048576 * 2);
  u16* Wb_out = (u16*)carve((size_t)65536 * 2);
  u16* Wh_e0f = (u16*)carve((size_t)1048576 * 2);
  u16* Wh_e0b = (u16*)carve((size_t)1048576 * 2);
  u16* Wh_e1f = (u16*)carve((size_t)1048576 * 2);
  u16* Wh_e1b = (u16*)carve((size_t)1048576 * 2);
  u16* Wh_d0  = (u16*)carve((size_t)1048576 * 2);
  u16* Wh_d1  = (u16*)carve((size_t)1048576 * 2);
  u16* slot0  = (u16*)carve((size_t)16384 * 2048 * 2);
  u16* slot1  = (u16*)carve((size_t)16384 * 2048 * 2);
  u16* l0     = (u16*)carve((size_t)33619968);  // l0 (32MB); later o1 + hxprod
  u16* hxring = (u16*)carve((size_t)524288);    // 8 chains x 64KB
  float* hcat = (float*)carve((size_t)65536 * 4);
  float* zws  = (float*)carve((size_t)8192 * 4);
  float* h0d  = (float*)carve((size_t)32768 * 4);
  u32* tags0  = (u32*)carve(2048);
  u32* tags1  = (u32*)carve(2048);
  u32* tags2  = (u32*)carve(2048);
  if (off > ws_size) return;

  u16* o1     = l0;                // alias: l0 dead after e1 gemms
  u16* hxprod = l0 + 8388608;      // +16MiB (u16 units)

  (void)hipMemsetAsync(tags0, 0, 6144, stream);

  k_prep_x<<<8192, 256, 0, stream>>>(x, start_tk, Ax, Axs, 2097152);
  {
    CvtJobs j{};
    const float* s[13] = {e0f_Wih, e0b_Wih, d0_Wih, e1f_Wih, e1b_Wih, d1_Wih, out_W,
                          e0f_Whh, e0b_Whh, e1f_Whh, e1b_Whh, d0_Whh, d1_Whh};
    u16* d[13] = {Wb_e0f, Wb_e0b, Wb_d0, Wb_e1f, Wb_e1b, Wb_d1, Wb_out,
                  Wh_e0f, Wh_e0b, Wh_e1f, Wh_e1b, Wh_d0, Wh_d1};
    int n[13] = {262144, 262144, 262144, 2097152, 2097152, 1048576, 65536,
                 1048576, 1048576, 1048576, 1048576, 1048576, 1048576};
    int acc = 0;
    for (int k = 0; k < 13; ++k) { j.src[k] = s[k]; j.dst[k] = d[k]; j.off[k] = acc; acc += n[k]; }
    j.off[13] = acc;
    k_cvt_all<<<(acc + 255) / 256, 256, 0, stream>>>(j, acc);
  }

  // encoder layer 0 projections + recurrence (16-block chains) -> l0
  k_gemm_bt<<<dim3(128, 16), 256, 0, stream>>>(Ax, Wb_e0f, e0f_b, slot0, nullptr, 16384, 2048, 128, 0);
  k_gemm_bt<<<dim3(128, 16), 256, 0, stream>>>(Ax, Wb_e0b, e0b_b, slot1, nullptr, 16384, 2048, 128, 0);
  {
    RecE r{};
    for (int ch = 0; ch < 8; ++ch) {
      int dir2 = ch >> 2, g = ch & 3;
      r.xW[ch] = dir2 ? slot1 : slot0;
      r.Whh[ch] = dir2 ? Wh_e0b : Wh_e0f;
      r.seq[ch] = l0; r.seqstride[ch] = 1024; r.coloff[ch] = dir2 ? 512 : 0;
      r.rev[ch] = dir2; r.hfin[ch] = nullptr; r.hfinstride[ch] = 0;
      r.grp[ch] = g;
      r.hxc[ch] = hxring + (size_t)ch * 32768;
    }
    r.tags = tags0;
    k_rec_e<<<128, 256, 0, stream>>>(r);
  }
  // encoder layer 1 projections + recurrence (16-block chains) -> hcat
  k_gemm_bt<<<dim3(128, 16), 256, 0, stream>>>(l0, Wb_e1f, e1f_b, slot0, nullptr, 16384, 2048, 1024, 0);
  k_gemm_bt<<<dim3(128, 16), 256, 0, stream>>>(l0, Wb_e1b, e1b_b, slot1, nullptr, 16384, 2048, 1024, 0);
  {
    RecE r{};
    for (int ch = 0; ch < 8; ++ch) {
      int dir2 = ch >> 2, g = ch & 3;
      r.xW[ch] = dir2 ? slot1 : slot0;
      r.Whh[ch] = dir2 ? Wh_e1b : Wh_e1f;
      r.seq[ch] = nullptr; r.seqstride[ch] = 0; r.coloff[ch] = 0;
      r.rev[ch] = dir2; r.hfin[ch] = hcat + (dir2 ? 512 : 0); r.hfinstride[ch] = 1024;
      r.grp[ch] = g;
      r.hxc[ch] = hxring + (size_t)ch * 32768;
    }
    r.tags = tags1;
    k_rec_e<<<128, 256, 0, stream>>>(r);
  }
  // bottleneck
  k_enc_head<<<64, 128, 0, stream>>>(hcat, enc_fc_W, enc_fc_b, zws, ((float*)d_out) + 2097152);
  k_dec_head<<<64, 512, 0, stream>>>(zws, dec_fc_W, dec_fc_b, h0d);
  // decoder: d0 projection, then fused d0||d1 recurrence (32-block chains) -> o1
  k_gemm_bt<<<dim3(128, 16), 256, 0, stream>>>(Axs, Wb_d0, d0_b, slot0, nullptr, 16384, 2048, 128, 0);
  {
    Rec2 r{};
    for (int ch = 0; ch < 4; ++ch) {  // d0 chains: full-depth producers
      r.xW[ch] = slot0;
      r.Whh[ch] = Wh_d0;
      r.Wih[ch] = nullptr; r.bias[ch] = nullptr; r.h0[ch] = h0d;
      r.seq[ch] = nullptr; r.seqstride[ch] = 0; r.coloff[ch] = 0;
      r.rev[ch] = 0; r.hfin[ch] = nullptr; r.hfinstride[ch] = 0;
      r.grp[ch] = ch; r.fused[ch] = 0; r.fullp[ch] = 1; r.prod[ch] = 0;
      r.hxc[ch] = hxprod + (size_t)ch * 2105344;  // 257*32*256 u16
    }
    for (int ch = 4; ch < 8; ++ch) {  // d1 chains: fused consumers
      r.xW[ch] = nullptr;
      r.Whh[ch] = Wh_d1;
      r.Wih[ch] = Wb_d1; r.bias[ch] = d1_b; r.h0[ch] = h0d;
      r.seq[ch] = o1; r.seqstride[ch] = 512; r.coloff[ch] = 0;
      r.rev[ch] = 0; r.hfin[ch] = nullptr; r.hfinstride[ch] = 0;
      r.grp[ch] = ch - 4; r.fused[ch] = 1; r.fullp[ch] = 0; r.prod[ch] = ch - 4;
      r.hxc[ch] = hxring + (size_t)ch * 32768;
    }
    r.tags = tags2;
    k_rec2<<<256, 256, 0, stream>>>(r);
  }
  // output projection + sigmoid
  k_gemm_bt<<<dim3(128, 1), 256, 0, stream>>>(o1, Wb_out, out_b, nullptr, (float*)d_out, 16384, 128, 512, 1);
}

// Round 15
// 5138.321 us; speedup vs baseline: 1.0971x; 1.0971x over previous
//
#include <hip/hip_runtime.h>
#include <stdint.h>

// LSTM autoencoder: B=64, T=256, P=128, H=512, LAT=128
// out = [x_hat (64*256*128 f32), z (64*128 f32)]
// R15 = revert to R13 (measured best, 5.16 ms): 16-block encoder chains,
// 32-block fused decoder chains, single-tag protocol with post-gate barrier.

typedef unsigned short u16;
typedef unsigned int u32;
typedef float f32x4 __attribute__((ext_vector_type(4)));
typedef __bf16 bf16x8 __attribute__((ext_vector_type(8)));
typedef unsigned int u32x4 __attribute__((ext_vector_type(4)));

#define AT_LD(p) __hip_atomic_load((p), __ATOMIC_RELAXED, __HIP_MEMORY_SCOPE_AGENT)
#define AT_ST(p, v) __hip_atomic_store((p), (v), __ATOMIC_RELAXED, __HIP_MEMORY_SCOPE_AGENT)

__device__ __forceinline__ u16 f2bf(float f) {
  u32 u = __builtin_bit_cast(u32, f);
  u += 0x7FFFu + ((u >> 16) & 1u);
  return (u16)(u >> 16);
}
__device__ __forceinline__ float bf2f(u16 h) {
  return __builtin_bit_cast(float, (u32)h << 16);
}
__device__ __forceinline__ bf16x8 ld8(const u16* p) {
  u32x4 v = *(const u32x4*)p;
  return __builtin_bit_cast(bf16x8, v);
}
__device__ __forceinline__ float sigf(float x) { return 1.f / (1.f + __expf(-x)); }
__device__ __forceinline__ float tanhx(float x) {
  x = fminf(fmaxf(x, -15.f), 15.f);
  float e = __expf(2.f * x);
  return (e - 1.f) / (e + 1.f);
}

// ---- prep kernels ----
__global__ void k_prep_x(const float* __restrict__ x, const float* __restrict__ st,
                         u16* __restrict__ Ax, u16* __restrict__ Axs, int n) {
  int i = blockIdx.x * 256 + threadIdx.x;
  if (i >= n) return;
  Ax[i] = f2bf(x[i]);
  int col = i & 127;
  int t = (i >> 7) & 255;
  float v = (t == 0) ? st[col] : x[i - 128];
  Axs[i] = f2bf(v);
}

// merged f32->bf16 conversions (13 jobs, prefix table)
struct CvtJobs {
  const float* src[13];
  u16* dst[13];
  int off[14];
};
__global__ void k_cvt_all(CvtJobs j, int total) {
  int i = blockIdx.x * 256 + threadIdx.x;
  if (i >= total) return;
  int a = 0;
#pragma unroll
  for (int k = 1; k < 13; ++k) a += (i >= j.off[k]) ? 1 : 0;
  int local = i - j.off[a];
  j.dst[a][local] = f2bf(j.src[a][local]);
}

// ---- bulk GEMM: C[M][N] = A[M][K] @ B'[N][K]^T + bias, bf16 in, fp32 acc ----
__global__ __launch_bounds__(256) void k_gemm_bt(
    const u16* __restrict__ A, const u16* __restrict__ B, const float* __restrict__ bias,
    u16* __restrict__ Cb, float* __restrict__ Cf, int M, int N, int K, int sig) {
  __shared__ __align__(16) u16 As[128 * 64];
  __shared__ __align__(16) u16 Bs[128 * 64];
  const int m0 = blockIdx.x * 128, n0 = blockIdx.y * 128;
  const int tid = threadIdx.x, lane = tid & 63, wave = tid >> 6;
  const int wm = wave >> 1, wn = wave & 1;

  f32x4 acc[4][4];
#pragma unroll
  for (int i = 0; i < 4; ++i)
#pragma unroll
    for (int j = 0; j < 4; ++j) acc[i][j] = (f32x4){0.f, 0.f, 0.f, 0.f};

  const int nkt = K >> 6;
  for (int kt = 0; kt < nkt; ++kt) {
#pragma unroll
    for (int i = 0; i < 4; ++i) {
      int ch = tid + (i << 8);
      int row = ch >> 3, k8 = ch & 7;
      int dst = row * 128 + ((k8 * 16) ^ ((row & 7) << 4));
      u32x4 va = *(const u32x4*)(A + (size_t)(m0 + row) * K + kt * 64 + k8 * 8);
      *(u32x4*)((char*)As + dst) = va;
      u32x4 vb = *(const u32x4*)(B + (size_t)(n0 + row) * K + kt * 64 + k8 * 8);
      *(u32x4*)((char*)Bs + dst) = vb;
    }
    __syncthreads();
#pragma unroll
    for (int kk = 0; kk < 2; ++kk) {
      int kb = kk * 64 + ((lane >> 4) << 4);
      bf16x8 afr[4], bfr[4];
#pragma unroll
      for (int i = 0; i < 4; ++i) {
        int ra = wm * 64 + i * 16 + (lane & 15);
        afr[i] = ld8((const u16*)((const char*)As + ra * 128 + (kb ^ ((ra & 7) << 4))));
        int rb = wn * 64 + i * 16 + (lane & 15);
        bfr[i] = ld8((const u16*)((const char*)Bs + rb * 128 + (kb ^ ((rb & 7) << 4))));
      }
#pragma unroll
      for (int i = 0; i < 4; ++i)
#pragma unroll
        for (int j = 0; j < 4; ++j)
          acc[i][j] = __builtin_amdgcn_mfma_f32_16x16x32_bf16(afr[i], bfr[j], acc[i][j], 0, 0, 0);
    }
    __syncthreads();
  }
#pragma unroll
  for (int i = 0; i < 4; ++i) {
#pragma unroll
    for (int j = 0; j < 4; ++j) {
      int col = n0 + wn * 64 + j * 16 + (lane & 15);
      float bv = bias ? bias[col] : 0.f;
#pragma unroll
      for (int r = 0; r < 4; ++r) {
        int row = m0 + wm * 64 + i * 16 + ((lane >> 4) << 2) + r;
        float v = acc[i][j][r] + bv;
        if (sig) Cf[(size_t)row * N + col] = 1.f / (1.f + __expf(-v));
        else     Cb[(size_t)row * N + col] = f2bf(v);
      }
    }
  }
}

// ---- encoder recurrence: 16-block chains (32 h-cols each) ----
// chain = bid&7, c = bid>>3 (0..15). Whh slice 128KB in LDS. Tag protocol,
// wave-0 poll (16 tags), LDS h staging, waves 2-3 gate math, row-major h-ring
// hx[slot:4][row:16][256 u32].
struct RecE {
  const u16* xW[8];      // bf16 [64][256][2048]
  const u16* Whh[8];     // bf16 [2048][512]
  u16* seq[8];           // bf16 seq out or null
  float* hfin[8];
  u16* hxc[8];
  int seqstride[8]; int coloff[8]; int rev[8]; int hfinstride[8];
  int grp[8];
  u32* tags;             // [chain][64]
};

__global__ __launch_bounds__(256, 1) void k_rec_e(RecE p) {
  const int chain = blockIdx.x & 7;
  const int c = blockIdx.x >> 3;  // 0..15
  const int tid = threadIdx.x, lane = tid & 63, wave = tid >> 6;  // wave = gate
  const int arow = lane & 15, kg = lane >> 4;

  const u16* __restrict__ xW = p.xW[chain];
  const u16* __restrict__ Whh = p.Whh[chain];
  u16* seq = p.seq[chain];
  float* hfin = p.hfin[chain];
  u32* hx = (u32*)p.hxc[chain];
  const int grp = p.grp[chain], rev = p.rev[chain];
  const int sstride = p.seqstride[chain], coloff = p.coloff[chain];
  const int hstride = p.hfinstride[chain];
  u32* myt = p.tags + chain * 64;

  __shared__ __align__(16) u16 Wlds[64][128][8];  // [k>>3][n][k&7], n=gate*32+col
  __shared__ __align__(16) u16 hbufA[8192];       // 16 rows x 512 cols, swizzled
  __shared__ float gbuf[4][16][32];
  __shared__ float cbuf[512];

  // Whh slice fill: n = gate*32 + local col
  for (int e = tid; e < 8192; e += 256) {
    int n = e >> 6, k8 = e & 63;
    int grow = ((n >> 5) << 9) + (c << 5) + (n & 31);
    *(u32x4*)(&Wlds[k8][n][0]) = *(const u32x4*)(Whh + (size_t)grow * 512 + k8 * 8);
  }
  for (int e = tid; e < 512; e += 256) cbuf[e] = 0.f;
  // publish h_0 = zeros (encoder always starts from 0) to slot 0
  for (int e = tid; e < 4096; e += 256) AT_ST(hx + e, 0u);
  asm volatile("s_waitcnt vmcnt(0)" ::: "memory");
  __syncthreads();
  if (tid == 0) AT_ST(myt + c, 1u);

  for (int t = 0; t < 256; ++t) {
    const int t_eff = rev ? 255 - t : t;
    const int slot = t & 3;
    const int slotn = (t + 1) & 3;

    // xW prefetch (gate=wave, cols c*32+arow / +16); drains under the poll
    float xwv[4][2];
#pragma unroll
    for (int r4 = 0; r4 < 4; ++r4) {
      int row = (kg << 2) + r4;
      const u16* xwp = xW + (((size_t)((grp * 16 + row) * 256 + t_eff)) << 11) +
                       (wave << 9) + (c << 5);
      xwv[r4][0] = bf2f(xwp[arow]);
      xwv[r4][1] = bf2f(xwp[arow + 16]);
    }
    // poll: wave 0 only, 16 tags (skip self), s_sleep backoff
    if (wave == 0) {
      u32 thr = (u32)(t + 1);
      while (true) {
        int ok = 1;
        if (lane < 16 && lane != c) ok = (AT_LD(myt + lane) >= thr);
        if (__all(ok)) break;
        __builtin_amdgcn_s_sleep(1);
      }
    }
    __syncthreads();
    __builtin_amdgcn_sched_barrier(0);

    // stage h_t into LDS (row-major ring, swizzled dst)
#pragma unroll
    for (int i = 0; i < 4; ++i) {
      int cid = tid + (i << 8);          // 0..1023: 16 rows x 64 16B-chunks
      int row = cid >> 6, ch8 = cid & 63;
      const u32* src = hx + slot * 4096 + row * 256 + ch8 * 4;
      u32x4 v;
      v.x = AT_LD(src + 0); v.y = AT_LD(src + 1);
      v.z = AT_LD(src + 2); v.w = AT_LD(src + 3);
      *(u32x4*)((char*)hbufA + row * 1024 + ((ch8 << 4) ^ ((row & 7) << 4))) = v;
    }
    __syncthreads();  // hbufA visible

    // A-fragments + MFMA (2 col-groups of 16)
    bf16x8 af[16];
#pragma unroll
    for (int kt = 0; kt < 16; ++kt)
      af[kt] = ld8((const u16*)((const char*)hbufA + arow * 1024 +
                                ((kt * 64 + (kg << 4)) ^ ((arow & 7) << 4))));
    f32x4 acc0 = {0.f, 0.f, 0.f, 0.f};
    f32x4 acc1 = {0.f, 0.f, 0.f, 0.f};
#pragma unroll
    for (int kt = 0; kt < 16; ++kt) {
      const u16* bp = &Wlds[(kt << 2) + kg][(wave << 5) + arow][0];
      bf16x8 b0 = ld8(bp);
      bf16x8 b1 = ld8(bp + 128);  // +16 columns
      acc0 = __builtin_amdgcn_mfma_f32_16x16x32_bf16(af[kt], b0, acc0, 0, 0, 0);
      acc1 = __builtin_amdgcn_mfma_f32_16x16x32_bf16(af[kt], b1, acc1, 0, 0, 0);
    }
#pragma unroll
    for (int r4 = 0; r4 < 4; ++r4) {
      gbuf[wave][(kg << 2) + r4][arow] = acc0[r4] + xwv[r4][0];
      gbuf[wave][(kg << 2) + r4][arow + 16] = acc1[r4] + xwv[r4][1];
    }
    __syncthreads();

    // gate math + publish: waves 2-3 only, 4 cells (2 u32) per thread
    u32 pk0 = 0, pk1 = 0; int row2 = 0, j0 = 0;
    float hhv[4] = {0.f, 0.f, 0.f, 0.f};
    if (tid >= 128) {
      int t2 = tid - 128;
      row2 = t2 >> 3; int q = t2 & 7; j0 = q << 2;
#pragma unroll
      for (int jj = 0; jj < 4; ++jj) {
        int col = j0 + jj;
        float iv = gbuf[0][row2][col];
        float fv = gbuf[1][row2][col];
        float gv = gbuf[2][row2][col];
        float ov = gbuf[3][row2][col];
        int ci = (row2 << 5) + col;
        float cc = sigf(fv) * cbuf[ci] + sigf(iv) * tanhx(gv);
        cbuf[ci] = cc;
        hhv[jj] = sigf(ov) * tanhx(cc);
      }
      pk0 = (u32)f2bf(hhv[0]) | ((u32)f2bf(hhv[1]) << 16);
      pk1 = (u32)f2bf(hhv[2]) | ((u32)f2bf(hhv[3]) << 16);
      u32* dst = hx + slotn * 4096 + row2 * 256 + (c << 4) + (q << 1);
      AT_ST(dst, pk0);
      AT_ST(dst + 1, pk1);
      asm volatile("s_waitcnt vmcnt(0)" ::: "memory");
    }
    __syncthreads();  // h stores drained before tag
    if (tid == 128) AT_ST(myt + c, (u32)(t + 2));
    if (tid >= 128) {
      // bulk outputs AFTER the tag: drain hides under the next poll
      if (seq) {
        u32* sp = (u32*)(seq + ((size_t)((grp * 16 + row2) * 256 + t_eff)) * sstride +
                         coloff + (c << 5) + j0);
        sp[0] = pk0; sp[1] = pk1;
      }
      if (hfin && t == 255) {
        float* hp = hfin + (size_t)(grp * 16 + row2) * hstride + (c << 5) + j0;
        hp[0] = hhv[0]; hp[1] = hhv[1]; hp[2] = hhv[2]; hp[3] = hhv[3];
      }
    }
  }
}

// ---- decoder recurrence (R12-verified, 32-block chains, fused d0||d1) ----
struct Rec2 {
  const u16* xW[8];
  const u16* Whh[8];
  const u16* Wih[8];
  const float* bias[8];
  const float* h0[8];
  u16* seq[8];
  float* hfin[8];
  u16* hxc[8];
  int prod[8];
  int seqstride[8]; int coloff[8]; int rev[8]; int hfinstride[8];
  int grp[8]; int fused[8]; int fullp[8];
  u32* tags;
};

__global__ __launch_bounds__(256, 1) void k_rec2(Rec2 p) {
  const int chain = blockIdx.x & 7;
  const int c = blockIdx.x >> 3;  // 0..31
  const int tid = threadIdx.x, lane = tid & 63, wave = tid >> 6;  // wave = gate
  const int arow = lane & 15, kg = lane >> 4;

  const u16* __restrict__ xW = p.xW[chain];
  const u16* __restrict__ Whh = p.Whh[chain];
  const u16* __restrict__ Wih = p.Wih[chain];
  const float* __restrict__ bias = p.bias[chain];
  const float* __restrict__ h0 = p.h0[chain];
  u16* seq = p.seq[chain];
  float* hfin = p.hfin[chain];
  u32* hx = (u32*)p.hxc[chain];
  const u32* hxp = (const u32*)p.hxc[p.prod[chain]];
  const int grp = p.grp[chain], rev = p.rev[chain];
  const int fused = p.fused[chain], fullp = p.fullp[chain];
  const int sstride = p.seqstride[chain], coloff = p.coloff[chain];
  const int hstride = p.hfinstride[chain];
  u32* myt = p.tags + chain * 64;
  const u32* pt = p.tags + p.prod[chain] * 64;

  __shared__ __align__(16) u16 Wlds[64][64][8];
  __shared__ __align__(16) u16 Xlds[64][64][8];
  __shared__ __align__(16) u16 hbufA[8192];
  __shared__ float gbuf[4][16][16];
  __shared__ float cbuf[256];
  __shared__ float bbuf[64];

  for (int e = tid; e < 4096; e += 256) {
    int n = e >> 6, k8 = e & 63;
    int grow = ((n >> 4) << 9) + (c << 4) + (n & 15);
    *(u32x4*)(&Wlds[k8][n][0]) = *(const u32x4*)(Whh + (size_t)grow * 512 + k8 * 8);
    if (fused)
      *(u32x4*)(&Xlds[k8][n][0]) = *(const u32x4*)(Wih + (size_t)grow * 512 + k8 * 8);
  }
  if (tid < 64) bbuf[tid] = fused ? bias[((tid >> 4) << 9) + (c << 4) + (tid & 15)] : 0.f;
  cbuf[tid] = 0.f;
  if (tid < 128) {
    int row = tid >> 3, q = tid & 7;
    float a = 0.f, b2 = 0.f;
    if (h0) {
      a = h0[(size_t)(grp * 16 + row) * 512 + (c << 4) + 2 * q];
      b2 = h0[(size_t)(grp * 16 + row) * 512 + (c << 4) + 2 * q + 1];
    }
    u32 pk = (u32)f2bf(a) | ((u32)f2bf(b2) << 16);
    AT_ST(hx + (size_t)c * 128 + (row << 3) + q, pk);
  }
  asm volatile("s_waitcnt vmcnt(0)" ::: "memory");
  __syncthreads();
  if (tid == 0) AT_ST(myt + c, 1u);

  for (int t = 0; t < 256; ++t) {
    const int t_eff = rev ? 255 - t : t;
    const int slot = fullp ? t : (t & 3);
    const int slotn = fullp ? (t + 1) : ((t + 1) & 3);

    float xwv[4] = {0.f, 0.f, 0.f, 0.f};
    if (!fused) {
#pragma unroll
      for (int r4 = 0; r4 < 4; ++r4) {
        int row = (kg << 2) + r4;
        xwv[r4] = bf2f(xW[(((size_t)((grp * 16 + row) * 256 + t_eff)) << 11) +
                          (wave << 9) + (c << 4) + arow]);
      }
    }
    if (wave == 0) {
      u32 thr_own = (u32)(t + 1), thr_prod = (u32)(t + 2);
      while (true) {
        int ok = 1;
        if (lane < 32) {
          if (lane != c) ok = (AT_LD(myt + lane) >= thr_own);
        } else if (fused) {
          ok = (AT_LD(pt + (lane - 32)) >= thr_prod);
        }
        if (__all(ok)) break;
        __builtin_amdgcn_s_sleep(1);
      }
    }
    __syncthreads();
    __builtin_amdgcn_sched_barrier(0);

#pragma unroll
    for (int i = 0; i < 4; ++i) {
      int cid = tid + (i << 8);
      int row = cid >> 6, ch8 = cid & 63;
      const u32* src = hx + ((size_t)slot * 32 + (ch8 >> 1)) * 128 +
                       (row << 3) + ((ch8 & 1) << 2);
      u32x4 v;
      v.x = AT_LD(src + 0); v.y = AT_LD(src + 1);
      v.z = AT_LD(src + 2); v.w = AT_LD(src + 3);
      *(u32x4*)((char*)hbufA + row * 1024 + ((ch8 << 4) ^ ((row & 7) << 4))) = v;
    }
    bf16x8 xf[16];
    if (fused) {
#pragma unroll
      for (int kt = 0; kt < 16; ++kt) {
        const u32* hp = hxp + ((size_t)(t + 1) * 32 + 2 * kt + (kg >> 1)) * 128 +
                        (arow << 3) + ((kg & 1) << 2);
        u32x4 v;
        v.x = AT_LD(hp + 0); v.y = AT_LD(hp + 1);
        v.z = AT_LD(hp + 2); v.w = AT_LD(hp + 3);
        xf[kt] = __builtin_bit_cast(bf16x8, v);
      }
    }
    __syncthreads();

    bf16x8 af[16];
#pragma unroll
    for (int kt = 0; kt < 16; ++kt)
      af[kt] = ld8((const u16*)((const char*)hbufA + arow * 1024 +
                                ((kt * 64 + (kg << 4)) ^ ((arow & 7) << 4))));
    f32x4 ae = {0.f, 0.f, 0.f, 0.f}, ao = {0.f, 0.f, 0.f, 0.f};
#pragma unroll
    for (int kt = 0; kt < 16; ++kt) {
      bf16x8 bw = ld8(&Wlds[(kt << 2) + kg][(wave << 4) + arow][0]);
      if (kt & 1) ao = __builtin_amdgcn_mfma_f32_16x16x32_bf16(af[kt], bw, ao, 0, 0, 0);
      else        ae = __builtin_amdgcn_mfma_f32_16x16x32_bf16(af[kt], bw, ae, 0, 0, 0);
      if (fused) {
        bf16x8 bx = ld8(&Xlds[(kt << 2) + kg][(wave << 4) + arow][0]);
        if (kt & 1) ae = __builtin_amdgcn_mfma_f32_16x16x32_bf16(xf[kt], bx, ae, 0, 0, 0);
        else        ao = __builtin_amdgcn_mfma_f32_16x16x32_bf16(xf[kt], bx, ao, 0, 0, 0);
      }
    }
#pragma unroll
    for (int r4 = 0; r4 < 4; ++r4)
      gbuf[wave][(kg << 2) + r4][arow] = ae[r4] + ao[r4] + xwv[r4];
    __syncthreads();

    u32 pk = 0; int row2 = 0, j0 = 0;
    float hh0 = 0.f, hh1 = 0.f;
    if (tid >= 128) {
      int t2 = tid - 128;
      row2 = t2 >> 3; int q = t2 & 7; j0 = q << 1;
      float i0 = gbuf[0][row2][j0], i1 = gbuf[0][row2][j0 + 1];
      float f0 = gbuf[1][row2][j0], f1 = gbuf[1][row2][j0 + 1];
      float g0 = gbuf[2][row2][j0], g1 = gbuf[2][row2][j0 + 1];
      float o0v = gbuf[3][row2][j0], o1v = gbuf[3][row2][j0 + 1];
      if (fused) {
        i0 += bbuf[j0]; i1 += bbuf[j0 + 1];
        f0 += bbuf[16 + j0]; f1 += bbuf[16 + j0 + 1];
        g0 += bbuf[32 + j0]; g1 += bbuf[32 + j0 + 1];
        o0v += bbuf[48 + j0]; o1v += bbuf[48 + j0 + 1];
      }
      int ci = (row2 << 4) + j0;
      float cc0 = sigf(f0) * cbuf[ci] + sigf(i0) * tanhx(g0);
      float cc1 = sigf(f1) * cbuf[ci + 1] + sigf(i1) * tanhx(g1);
      cbuf[ci] = cc0; cbuf[ci + 1] = cc1;
      hh0 = sigf(o0v) * tanhx(cc0);
      hh1 = sigf(o1v) * tanhx(cc1);
      pk = (u32)f2bf(hh0) | ((u32)f2bf(hh1) << 16);
      AT_ST(hx + ((size_t)slotn * 32 + c) * 128 + (row2 << 3) + q, pk);
      asm volatile("s_waitcnt vmcnt(0)" ::: "memory");
    }
    __syncthreads();
    if (tid == 128) AT_ST(myt + c, (u32)(t + 2));
    if (tid >= 128) {
      if (seq)
        *(u32*)(seq + ((size_t)((grp * 16 + row2) * 256 + t_eff)) * sstride +
                coloff + (c << 4) + j0) = pk;
      if (hfin && t == 255) {
        hfin[(size_t)(grp * 16 + row2) * hstride + (c << 4) + j0] = hh0;
        hfin[(size_t)(grp * 16 + row2) * hstride + (c << 4) + j0 + 1] = hh1;
      }
    }
  }
}

// ---- tiny heads ----
__global__ void k_enc_head(const float* __restrict__ hcat, const float* __restrict__ W,
                           const float* __restrict__ b, float* __restrict__ zws,
                           float* __restrict__ zout) {
  int bi = blockIdx.x, j = threadIdx.x;
  const float* h = hcat + bi * 1024;
  const float* w = W + j * 1024;
  float s = b[j];
  for (int k = 0; k < 1024; ++k) s += h[k] * w[k];
  zws[bi * 128 + j] = s;
  zout[bi * 128 + j] = s;
}

__global__ void k_dec_head(const float* __restrict__ z, const float* __restrict__ W,
                           const float* __restrict__ b, float* __restrict__ h0d) {
  int bi = blockIdx.x, j = threadIdx.x;
  const float* zz = z + bi * 128;
  const float* w = W + j * 128;
  float s = b[j];
  for (int k = 0; k < 128; ++k) s += zz[k] * w[k];
  h0d[bi * 512 + j] = s;
}

extern "C" void kernel_launch(void* const* d_in, const int* in_sizes, int n_in,
                              void* d_out, int out_size, void* d_ws, size_t ws_size,
                              hipStream_t stream) {
  (void)in_sizes; (void)n_in; (void)out_size;
  const float* x        = (const float*)d_in[0];
  const float* e0f_Wih  = (const float*)d_in[1];
  const float* e0f_Whh  = (const float*)d_in[2];
  const float* e0f_b    = (const float*)d_in[3];
  const float* e0b_Wih  = (const float*)d_in[4];
  const float* e0b_Whh  = (const float*)d_in[5];
  const float* e0b_b    = (const float*)d_in[6];
  const float* e1f_Wih  = (const float*)d_in[7];
  const float* e1f_Whh  = (const float*)d_in[8];
  const float* e1f_b    = (const float*)d_in[9];
  const float* e1b_Wih  = (const float*)d_in[10];
  const float* e1b_Whh  = (const float*)d_in[11];
  const float* e1b_b    = (const float*)d_in[12];
  const float* enc_fc_W = (const float*)d_in[13];
  const float* enc_fc_b = (const float*)d_in[14];
  const float* dec_fc_W = (const float*)d_in[15];
  const float* dec_fc_b = (const float*)d_in[16];
  const float* start_tk = (const float*)d_in[17];
  const float* d0_Wih   = (const float*)d_in[18];
  const float* d0_Whh   = (const float*)d_in[19];
  const float* d0_b     = (const float*)d_in[20];
  const float* d1_Wih   = (const float*)d_in[21];
  const float* d1_Whh   = (const float*)d_in[22];
  const float* d1_b     = (const float*)d_in[23];
  const float* out_W    = (const float*)d_in[24];
  const float* out_b    = (const float*)d_in[25];

  uintptr_t base = (uintptr_t)d_ws;
  size_t off = 0;
  auto carve = [&](size_t bytes) -> void* {
    off = (off + 255) & ~(size_t)255;
    void* p = (void*)(base + off);
    off += bytes;
    return p;
  };
  u16* Ax     = (u16*)carve((size_t)2097152 * 2);
  u16* Axs    = (u16*)carve((size_t)2097152 * 2);
  u16* Wb_e0f = (u16*)carve((size_t)262144 * 2);
  u16* Wb_e0b = (u16*)carve((size_t)262144 * 2);
  u16* Wb_d0  = (u16*)carve((size_t)262144 * 2);
  u16* Wb_e1f = (u16*)carve((size_t)2097152 * 2);
  u16* Wb_e1b = (u16*)carve((size_t)2097152 * 2);
  u16* Wb_d1  = (u16*)carve((size_t)1048576 * 2);
  u16* Wb_out = (u16*)carve((size_t)65536 * 2);
  u16* Wh_e0f = (u16*)carve((size_t)1048576 * 2);
  u16* Wh_e0b = (u16*)carve((size_t)1048576 * 2);
  u16* Wh_e1f = (u16*)carve((size_t)1048576 * 2);
  u16* Wh_e1b = (u16*)carve((size_t)1048576 * 2);
  u16* Wh_d0  = (u16*)carve((size_t)1048576 * 2);
  u16* Wh_d1  = (u16*)carve((size_t)1048576 * 2);
  u16* slot0  = (u16*)carve((size_t)16384 * 2048 * 2);
  u16* slot1  = (u16*)carve((size_t)16384 * 2048 * 2);
  u16* l0     = (u16*)carve((size_t)33619968);  // l0 (32MB); later o1 + hxprod
  u16* hxring = (u16*)carve((size_t)524288);    // 8 chains x 64KB
  float* hcat = (float*)carve((size_t)65536 * 4);
  float* zws  = (float*)carve((size_t)8192 * 4);
  float* h0d  = (float*)carve((size_t)32768 * 4);
  u32* tags0  = (u32*)carve(2048);
  u32* tags1  = (u32*)carve(2048);
  u32* tags2  = (u32*)carve(2048);
  if (off > ws_size) return;

  u16* o1     = l0;                // alias: l0 dead after e1 gemms
  u16* hxprod = l0 + 8388608;      // +16MiB (u16 units)

  (void)hipMemsetAsync(tags0, 0, 6144, stream);

  k_prep_x<<<8192, 256, 0, stream>>>(x, start_tk, Ax, Axs, 2097152);
  {
    CvtJobs j{};
    const float* s[13] = {e0f_Wih, e0b_Wih, d0_Wih, e1f_Wih, e1b_Wih, d1_Wih, out_W,
                          e0f_Whh, e0b_Whh, e1f_Whh, e1b_Whh, d0_Whh, d1_Whh};
    u16* d[13] = {Wb_e0f, Wb_e0b, Wb_d0, Wb_e1f, Wb_e1b, Wb_d1, Wb_out,
                  Wh_e0f, Wh_e0b, Wh_e1f, Wh_e1b, Wh_d0, Wh_d1};
    int n[13] = {262144, 262144, 262144, 2097152, 2097152, 1048576, 65536,
                 1048576, 1048576, 1048576, 1048576, 1048576, 1048576};
    int acc = 0;
    for (int k = 0; k < 13; ++k) { j.src[k] = s[k]; j.dst[k] = d[k]; j.off[k] = acc; acc += n[k]; }
    j.off[13] = acc;
    k_cvt_all<<<(acc + 255) / 256, 256, 0, stream>>>(j, acc);
  }

  // encoder layer 0 projections + recurrence (16-block chains) -> l0
  k_gemm_bt<<<dim3(128, 16), 256, 0, stream>>>(Ax, Wb_e0f, e0f_b, slot0, nullptr, 16384, 2048, 128, 0);
  k_gemm_bt<<<dim3(128, 16), 256, 0, stream>>>(Ax, Wb_e0b, e0b_b, slot1, nullptr, 16384, 2048, 128, 0);
  {
    RecE r{};
    for (int ch = 0; ch < 8; ++ch) {
      int dir2 = ch >> 2, g = ch & 3;
      r.xW[ch] = dir2 ? slot1 : slot0;
      r.Whh[ch] = dir2 ? Wh_e0b : Wh_e0f;
      r.seq[ch] = l0; r.seqstride[ch] = 1024; r.coloff[ch] = dir2 ? 512 : 0;
      r.rev[ch] = dir2; r.hfin[ch] = nullptr; r.hfinstride[ch] = 0;
      r.grp[ch] = g;
      r.hxc[ch] = hxring + (size_t)ch * 32768;
    }
    r.tags = tags0;
    k_rec_e<<<128, 256, 0, stream>>>(r);
  }
  // encoder layer 1 projections + recurrence (16-block chains) -> hcat
  k_gemm_bt<<<dim3(128, 16), 256, 0, stream>>>(l0, Wb_e1f, e1f_b, slot0, nullptr, 16384, 2048, 1024, 0);
  k_gemm_bt<<<dim3(128, 16), 256, 0, stream>>>(l0, Wb_e1b, e1b_b, slot1, nullptr, 16384, 2048, 1024, 0);
  {
    RecE r{};
    for (int ch = 0; ch < 8; ++ch) {
      int dir2 = ch >> 2, g = ch & 3;
      r.xW[ch] = dir2 ? slot1 : slot0;
      r.Whh[ch] = dir2 ? Wh_e1b : Wh_e1f;
      r.seq[ch] = nullptr; r.seqstride[ch] = 0; r.coloff[ch] = 0;
      r.rev[ch] = dir2; r.hfin[ch] = hcat + (dir2 ? 512 : 0); r.hfinstride[ch] = 1024;
      r.grp[ch] = g;
      r.hxc[ch] = hxring + (size_t)ch * 32768;
    }
    r.tags = tags1;
    k_rec_e<<<128, 256, 0, stream>>>(r);
  }
  // bottleneck
  k_enc_head<<<64, 128, 0, stream>>>(hcat, enc_fc_W, enc_fc_b, zws, ((float*)d_out) + 2097152);
  k_dec_head<<<64, 512, 0, stream>>>(zws, dec_fc_W, dec_fc_b, h0d);
  // decoder: d0 projection, then fused d0||d1 recurrence (32-block chains) -> o1
  k_gemm_bt<<<dim3(128, 16), 256, 0, stream>>>(Axs, Wb_d0, d0_b, slot0, nullptr, 16384, 2048, 128, 0);
  {
    Rec2 r{};
    for (int ch = 0; ch < 4; ++ch) {  // d0 chains: full-depth producers
      r.xW[ch] = slot0;
      r.Whh[ch] = Wh_d0;
      r.Wih[ch] = nullptr; r.bias[ch] = nullptr; r.h0[ch] = h0d;
      r.seq[ch] = nullptr; r.seqstride[ch] = 0; r.coloff[ch] = 0;
      r.rev[ch] = 0; r.hfin[ch] = nullptr; r.hfinstride[ch] = 0;
      r.grp[ch] = ch; r.fused[ch] = 0; r.fullp[ch] = 1; r.prod[ch] = 0;
      r.hxc[ch] = hxprod + (size_t)ch * 2105344;  // 257*32*256 u16
    }
    for (int ch = 4; ch < 8; ++ch) {  // d1 chains: fused consumers
      r.xW[ch] = nullptr;
      r.Whh[ch] = Wh_d1;
      r.Wih[ch] = Wb_d1; r.bias[ch] = d1_b; r.h0[ch] = h0d;
      r.seq[ch] = o1; r.seqstride[ch] = 512; r.coloff[ch] = 0;
      r.rev[ch] = 0; r.hfin[ch] = nullptr; r.hfinstride[ch] = 0;
      r.grp[ch] = ch - 4; r.fused[ch] = 1; r.fullp[ch] = 0; r.prod[ch] = ch - 4;
      r.hxc[ch] = hxring + (size_t)ch * 32768;
    }
    r.tags = tags2;
    k_rec2<<<256, 256, 0, stream>>>(r);
  }
  // output projection + sigmoid
  k_gemm_bt<<<dim3(128, 1), 256, 0, stream>>>(o1, Wb_out, out_b, nullptr, (float*)d_out, 16384, 128, 512, 1);
}